// Round 3
// baseline (1875.005 us; speedup 1.0000x reference)
//
#include <hip/hip_runtime.h>
#include <cstdint>

// ---------------- common types / helpers ----------------
typedef short s16x8 __attribute__((ext_vector_type(8)));
typedef __bf16 b16x8 __attribute__((ext_vector_type(8)));
typedef float f32x4 __attribute__((ext_vector_type(4)));
typedef float f32x16 __attribute__((ext_vector_type(16)));

#define TSEQ 2048
#define EDIM 1024

__device__ __forceinline__ short f2bf(float x) {  // RTNE float->bf16
  unsigned u = __float_as_uint(x);
  unsigned r = (u + 0x7FFFu + ((u >> 16) & 1u)) >> 16;
  return (short)r;
}

__device__ __forceinline__ f32x4 mfma16(s16x8 a, s16x8 b, f32x4 c) {
  return __builtin_amdgcn_mfma_f32_16x16x32_bf16(
      __builtin_bit_cast(b16x8, a), __builtin_bit_cast(b16x8, b), c, 0, 0, 0);
}

__device__ __forceinline__ f32x16 mfma32(s16x8 a, s16x8 b, f32x16 c) {
  return __builtin_amdgcn_mfma_f32_32x32x16_bf16(
      __builtin_bit_cast(b16x8, a), __builtin_bit_cast(b16x8, b), c, 0, 0, 0);
}

// async global->LDS, 16B/lane; lds base wave-uniform, lane i -> base + i*16
__device__ __forceinline__ void gl_lds16(void* lds, const void* g) {
  __builtin_amdgcn_global_load_lds(
      (const __attribute__((address_space(1))) void*)g,
      (__attribute__((address_space(3))) void*)lds, 16, 0, 0);
}

// ---------------- weight transpose + fp32->bf16 convert (all layers) ----------------
__global__ __launch_bounds__(256) void cvtTL(
    const float* __restrict__ W0, short* __restrict__ WT0, int K, int N) {
  const float* W = W0 + (size_t)blockIdx.y * K * N;
  short* WT = WT0 + (size_t)blockIdx.y * K * N;
  int t = blockIdx.x;
  const int tn = N >> 5;
  const int bn = (t % tn) << 5, bk = (t / tn) << 5;
  __shared__ float tile[32][33];
  const int tx = threadIdx.x & 31, ty = threadIdx.x >> 5;
#pragma unroll
  for (int i = 0; i < 4; ++i)
    tile[ty + i * 8][tx] = W[(size_t)(bk + ty + i * 8) * N + bn + tx];
  __syncthreads();
#pragma unroll
  for (int i = 0; i < 4; ++i)
    WT[(size_t)(bn + ty + i * 8) * K + bk + tx] = f2bf(tile[tx][ty + i * 8]);
}

// ---------------- layernorm: fp32 in -> bf16 out ----------------
__global__ __launch_bounds__(256) void ln_kernel(
    const float* __restrict__ h, const float* __restrict__ w,
    const float* __restrict__ b, short* __restrict__ y) {
  const int row = blockIdx.x, tid = threadIdx.x;
  const float4 v = ((const float4*)(h + (size_t)row * EDIM))[tid];
  float s = v.x + v.y + v.z + v.w;
  float s2 = v.x * v.x + v.y * v.y + v.z * v.z + v.w * v.w;
#pragma unroll
  for (int off = 1; off < 64; off <<= 1) {
    s += __shfl_xor(s, off, 64);
    s2 += __shfl_xor(s2, off, 64);
  }
  __shared__ float red[8];
  const int wave = tid >> 6, lane = tid & 63;
  if (lane == 0) { red[wave] = s; red[4 + wave] = s2; }
  __syncthreads();
  s = red[0] + red[1] + red[2] + red[3];
  s2 = red[4] + red[5] + red[6] + red[7];
  const float mu = s * (1.f / EDIM);
  const float var = s2 * (1.f / EDIM) - mu * mu;
  const float rstd = rsqrtf(var + 1e-5f);
  const float4 wv = ((const float4*)w)[tid];
  const float4 bv = ((const float4*)b)[tid];
  short4 o = make_short4(f2bf((v.x - mu) * rstd * wv.x + bv.x),
                         f2bf((v.y - mu) * rstd * wv.y + bv.y),
                         f2bf((v.z - mu) * rstd * wv.z + bv.z),
                         f2bf((v.w - mu) * rstd * wv.w + bv.w));
  ((short4*)(y + (size_t)row * EDIM))[tid] = o;
}

// ---------------- GEMM: C[M,N] = A[M,K](bf16) * BT[N,K]^T + bias ----------------
// BMx128 tile, BK=64, 4 waves, double-buffered LDS, 2-phase pipeline:
// STAGE(t+1) issued before compute(t), ONE barrier per K-step. 32x32x16 MFMA
// (wave tile 64x64 = 2x2 frags for BM=128): halves issue slots vs 16x16x32 and
// runs at the higher 32x32 rate (2495 vs 2176 TF ubench). LDS reads XOR-
// swizzled via inverse-swizzled global_load_lds SOURCE (linear dest, rule #21).
// A/B frag: row/col = lane&31, k = 8*(lane>>5)+e (K-doubling pattern of the
// verified 16x16x32 layout). C/D: col=lane&31, row=(r&3)+8*(r>>2)+4*(lane>>5)
// [HW-verified m74/m101].
// EPI 0: QKV split  EPI 1: atomicAdd into out_f (split-K; z==0 adds bias)
// EPI 2: gelu, bf16 out
template <int EPI, int BM>
__global__ __launch_bounds__(256, 2) void gemm_bt(
    const short* __restrict__ A, const short* __restrict__ BT,
    const float* __restrict__ bias, short* __restrict__ out_bf,
    short* __restrict__ vt, float* __restrict__ out_f,
    int M, int N, int K) {
  constexpr int WM = BM / 2;    // wave tile rows (64 or 32)
  constexpr int NMI = WM / 32;  // 32-row frag count (2 or 1)
  constexpr int ASZ = BM * 64;  // shorts per A buffer
  constexpr int BSZ = 128 * 64;
  __shared__ __align__(16) short As[2 * ASZ];
  __shared__ __align__(16) short Bs[2 * BSZ];
  const int tid = threadIdx.x;
  const int wave = tid >> 6, lane = tid & 63;
  const int l32 = lane & 31, kh = lane >> 5, rsw = l32 & 7;
  const int wr = (wave >> 1) * WM, wc = (wave & 1) * 64;
  const int m0 = blockIdx.y * BM, n0 = blockIdx.x * 128;
  const int ksplit = K / gridDim.z;  // K-range per z-slice
  const int kbase = blockIdx.z * ksplit;

  // staging source (per-lane), chunk XOR-swizzled so linear-dest LDS reads
  // back conflict-free with the same XOR on the read side.
  const int r8 = lane >> 3, c8 = lane & 7;
  const int csw = (c8 ^ r8) << 3;  // element offset within 64-elem row
  const short* Ag = A + (size_t)(m0 + wave * (BM / 4) + r8) * K + kbase + csw;
  const short* Bg = BT + (size_t)(n0 + wave * 32 + r8) * K + kbase + csw;

  f32x16 acc[NMI][2] = {};
  const int NT = ksplit >> 6;

  // prologue: stage tile 0 into buffer 0
#pragma unroll
  for (int c = 0; c < BM / 32; ++c)
    gl_lds16(&As[(wave * (BM / 32) + c) * 512], Ag + (size_t)(8 * c) * K);
#pragma unroll
  for (int c = 0; c < 4; ++c)
    gl_lds16(&Bs[(wave * 4 + c) * 512], Bg + (size_t)(8 * c) * K);
  __syncthreads();

  int cur = 0;
  for (int t = 0; t < NT; ++t) {
    if (t + 1 < NT) {  // issue next-tile stage into buf cur^1 (overlaps MFMA)
      const size_t ko = (size_t)(t + 1) << 6;
#pragma unroll
      for (int c = 0; c < BM / 32; ++c)
        gl_lds16(&As[(cur ^ 1) * ASZ + (wave * (BM / 32) + c) * 512],
                 Ag + (size_t)(8 * c) * K + ko);
#pragma unroll
      for (int c = 0; c < 4; ++c)
        gl_lds16(&Bs[(cur ^ 1) * BSZ + (wave * 4 + c) * 512],
                 Bg + (size_t)(8 * c) * K + ko);
    }
    const short* Ab = &As[cur * ASZ];
    const short* Bb = &Bs[cur * BSZ];
#pragma unroll
    for (int ks = 0; ks < 4; ++ks) {  // K-slices of 16
      const int chk = ((ks * 2 + kh) ^ rsw) << 3;
      s16x8 af[NMI], bfv[2];
#pragma unroll
      for (int mi = 0; mi < NMI; ++mi)
        af[mi] = *(const s16x8*)&Ab[(wr + mi * 32 + l32) * 64 + chk];
#pragma unroll
      for (int ni = 0; ni < 2; ++ni)
        bfv[ni] = *(const s16x8*)&Bb[(wc + ni * 32 + l32) * 64 + chk];
#pragma unroll
      for (int mi = 0; mi < NMI; ++mi)
#pragma unroll
        for (int ni = 0; ni < 2; ++ni)
          acc[mi][ni] = mfma32(af[mi], bfv[ni], acc[mi][ni]);
    }
    __syncthreads();  // drains vmcnt: next buffer resident; LDS reads done
    cur ^= 1;
  }

#pragma unroll
  for (int mi = 0; mi < NMI; ++mi) {
#pragma unroll
    for (int ni = 0; ni < 2; ++ni) {
      const int col = n0 + wc + ni * 32 + l32;
      const float bv = (EPI == 1 && blockIdx.z != 0) ? 0.f : bias[col];
#pragma unroll
      for (int r = 0; r < 16; ++r) {
        const int row = m0 + wr + mi * 32 + (r & 3) + 8 * (r >> 2) + 4 * kh;
        float v = acc[mi][ni][r] + bv;
        if (EPI == 1) {  // split-K accumulate; out_f already holds residual
          atomicAdd(&out_f[(size_t)row * N + col], v);
        } else if (EPI == 2) {
          const float u = 0.7978845608028654f * (v + 0.044715f * v * v * v);
          const float e = __expf(2.f * u);  // tanh(u) = 1 - 2/(e^{2u}+1)
          const float th = 1.f - 2.f / (e + 1.f);
          out_bf[(size_t)row * N + col] = f2bf(0.5f * v * (1.f + th));
        } else {  // QKV
          if (col < 2048)
            out_bf[(size_t)row * 2048 + col] = f2bf(v);
          else
            vt[(size_t)(col - 2048) * TSEQ + row] = f2bf(v);  // V^T [1024][T]
        }
      }
    }
  }
}

// ---------------- fused causal flash attention ----------------
// 4 waves / block, 64 q-rows (16/wave). K and V^T tiles staged cooperatively
// into LDS with global_load_lds (linear dest) + inverse-XOR-swizzled global
// source; reads apply the same XOR -> conflict-free ds_read_b128.
// P buffer is wave-private -> no barrier between P write and PV read.
// Grid (32,16): head y and y+8 at same x get depths s and 31-s (sum const)
// so each CU's 2 blocks carry uniform combined causal work.
__global__ __launch_bounds__(256) void attn_fused(
    const short* __restrict__ qk,  // [T][2048]: q cols h*64.., k cols 1024+h*64..
    const short* __restrict__ vt,  // [1024][T] = V^T rows (h*64+dh)
    short* __restrict__ aout) {    // [T][1024] bf16
  const int head = blockIdx.y;
  const int sidx = (blockIdx.x + 4 * (head & 7)) & 31;
  const int qg = (head < 8) ? sidx : 31 - sidx;  // q-group 0..31 (64 rows each)
  const int qbase = qg << 6;
  const int qt_end = qg >> 1;  // last 128-wide kv tile (causal)

  const int tid = threadIdx.x;
  const int wave = tid >> 6, lane = tid & 63;
  const int quad = lane >> 4, l16 = lane & 15;
  const int qrow = qbase + wave * 16;

  __shared__ __align__(16) short Ks[128 * 64];     // [krow][dh], XOR-swz, 16 KB
  __shared__ __align__(16) short Vs[64 * 128];     // [dh][kcol], XOR-swz, 16 KB
  __shared__ __align__(16) short ps[4][16 * 136];  // per-wave P tile, padded
  short* psw = ps[wave];

  s16x8 qf[2];
#pragma unroll
  for (int ks = 0; ks < 2; ++ks)
    qf[ks] = *(const s16x8*)&qk[(size_t)(qrow + l16) * 2048 +
                                head * 64 + ks * 32 + quad * 8];

  const int krow_off = tid >> 3;                       // 0..31
  const int kchk = ((tid & 7) ^ (krow_off & 7)) * 8;   // K src chunk (elements)
  const int vrow_off = tid >> 4;                       // 0..15
  const int vchk = ((tid & 15) ^ vrow_off) * 8;        // V src chunk (elements)

  const float scale = 0.125f;  // 1/sqrt(64)
  float mrow[4], lrow[4];
  f32x4 oacc[4] = {};
#pragma unroll
  for (int r = 0; r < 4; ++r) { mrow[r] = -1e30f; lrow[r] = 0.f; }

  for (int kt = 0; kt <= qt_end; ++kt) {
    const int k0 = kt << 7;
    // ---- stage K[128][64] + V^T[64][128] (32 KB, all 4 waves) ----
#pragma unroll
    for (int c = 0; c < 4; ++c) {
      gl_lds16(&Ks[c * 2048 + wave * 512],
               qk + (size_t)(k0 + c * 32 + krow_off) * 2048 + 1024 + head * 64 + kchk);
      gl_lds16(&Vs[c * 2048 + wave * 512],
               vt + (size_t)(head * 64 + c * 16 + vrow_off) * TSEQ + k0 + vchk);
    }
    __syncthreads();  // drains vmcnt: tiles resident

    // ---- QK^T ----
    f32x4 s[8] = {};
    __builtin_amdgcn_s_setprio(1);
#pragma unroll
    for (int ni = 0; ni < 8; ++ni) {
      const int kr = ni * 16 + l16;
      const int sw = kr & 7;
      s16x8 kf0 = *(const s16x8*)((const char*)Ks + kr * 128 + ((quad ^ sw) << 4));
      s16x8 kf1 = *(const s16x8*)((const char*)Ks + kr * 128 + ((quad ^ 4 ^ sw) << 4));
      s[ni] = mfma16(qf[0], kf0, s[ni]);
      s[ni] = mfma16(qf[1], kf1, s[ni]);
    }
    __builtin_amdgcn_s_setprio(0);

    // ---- online softmax ----
    const bool diag = (kt == qt_end);
    float rmax[4] = {-1e30f, -1e30f, -1e30f, -1e30f};
#pragma unroll
    for (int ni = 0; ni < 8; ++ni)
#pragma unroll
      for (int r = 0; r < 4; ++r) {
        float v = s[ni][r] * scale;
        if (diag) {
          const int qa = qrow + quad * 4 + r;
          const int ka = k0 + ni * 16 + l16;
          if (ka > qa) v = -1e30f;
        }
        s[ni][r] = v;
        rmax[r] = fmaxf(rmax[r], v);
      }
#pragma unroll
    for (int off = 1; off < 16; off <<= 1)
#pragma unroll
      for (int r = 0; r < 4; ++r)
        rmax[r] = fmaxf(rmax[r], __shfl_xor(rmax[r], off, 64));
    float al[4];
#pragma unroll
    for (int r = 0; r < 4; ++r) {
      const float mnew = fmaxf(mrow[r], rmax[r]);
      al[r] = __expf(mrow[r] - mnew);
      mrow[r] = mnew;
      lrow[r] *= al[r];
    }
#pragma unroll
    for (int ni = 0; ni < 4; ++ni)
#pragma unroll
      for (int r = 0; r < 4; ++r) oacc[ni][r] *= al[r];
    float psum[4] = {};
#pragma unroll
    for (int ni = 0; ni < 8; ++ni)
#pragma unroll
      for (int r = 0; r < 4; ++r) {
        const float p = __expf(s[ni][r] - mrow[r]);
        psum[r] += p;
        psw[(quad * 4 + r) * 136 + ni * 16 + l16] = f2bf(p);
      }
#pragma unroll
    for (int off = 1; off < 16; off <<= 1)
#pragma unroll
      for (int r = 0; r < 4; ++r) psum[r] += __shfl_xor(psum[r], off, 64);
#pragma unroll
    for (int r = 0; r < 4; ++r) lrow[r] += psum[r];

    // ---- PV (P wave-private: no barrier needed) ----
    __builtin_amdgcn_s_setprio(1);
#pragma unroll
    for (int ks = 0; ks < 4; ++ks) {
      s16x8 pa = *(const s16x8*)&psw[l16 * 136 + ks * 32 + quad * 8];
#pragma unroll
      for (int ni = 0; ni < 4; ++ni) {
        const int vr = ni * 16 + l16;
        s16x8 vf = *(const s16x8*)((const char*)Vs + vr * 256 +
                                   ((((ks << 2) | quad) ^ (vr & 15)) << 4));
        oacc[ni] = mfma16(pa, vf, oacc[ni]);
      }
    }
    __builtin_amdgcn_s_setprio(0);
    __syncthreads();  // all waves done with Ks/Vs before next stage
  }

#pragma unroll
  for (int ni = 0; ni < 4; ++ni)
#pragma unroll
    for (int r = 0; r < 4; ++r) {
      const int qa = qrow + quad * 4 + r;
      aout[(size_t)qa * EDIM + head * 64 + ni * 16 + l16] =
          f2bf(oacc[ni][r] / lrow[r]);
    }
}

// ---------------- launch ----------------
extern "C" void kernel_launch(void* const* d_in, const int* in_sizes, int n_in,
                              void* d_out, int out_size, void* d_ws, size_t ws_size,
                              hipStream_t stream) {
  const float* x     = (const float*)d_in[0];
  const float* ln1w  = (const float*)d_in[1];
  const float* ln1b  = (const float*)d_in[2];
  const float* attw  = (const float*)d_in[3];
  const float* attb  = (const float*)d_in[4];
  const float* projw = (const float*)d_in[5];
  const float* projb = (const float*)d_in[6];
  const float* ln2w  = (const float*)d_in[7];
  const float* ln2b  = (const float*)d_in[8];
  const float* fcw   = (const float*)d_in[9];
  const float* fcb   = (const float*)d_in[10];
  const float* fc2w  = (const float*)d_in[11];
  const float* fc2b  = (const float*)d_in[12];

  // workspace: harness re-poison fills 512 MB -> ws_size >= 512 MB.
  // [0,36) MB: activation pool (as before). [36,228) MB: all-layer
  // pre-transposed bf16 weights (attnT 48 + projT 16 + fcT 64 + fc2T 64).
  char* ws = (char*)d_ws;
  float* h   = (float*)(ws);               // [0,8)   residual fp32, persistent
  short* y   = (short*)(ws + (8u << 20));  // [8,12)  LN out bf16 / att (reused)
  short* att = (short*)(ws + (8u << 20));
  short* qkb = (short*)(ws + (12u << 20)); // [12,20) q,k bf16 [T][2048]
  short* vt  = (short*)(ws + (20u << 20)); // [20,24) V^T bf16 [1024][T]
  short* mid = (short*)(ws + (12u << 20)); // [12,28) gelu(fc) bf16 (reuses qkb/vt)
  short* attnT = (short*)(ws + (36u << 20));                 // 8 x 3M shorts
  short* projT = attnT + (size_t)8 * 3072 * 1024;            // 8 x 1M
  short* fcT   = projT + (size_t)8 * 1024 * 1024;            // 8 x 4M
  short* fc2T  = fcT + (size_t)8 * 1024 * 4096;              // 8 x 4M

  hipMemcpyAsync(h, x, (size_t)TSEQ * EDIM * 4, hipMemcpyDeviceToDevice, stream);

  // ---- pre-transpose all weights (4 batched launches) ----
  cvtTL<<<dim3((3072 / 32) * (1024 / 32), 8), 256, 0, stream>>>(attw, attnT, 1024, 3072);
  cvtTL<<<dim3((1024 / 32) * (1024 / 32), 8), 256, 0, stream>>>(projw, projT, 1024, 1024);
  cvtTL<<<dim3((4096 / 32) * (1024 / 32), 8), 256, 0, stream>>>(fcw, fcT, 1024, 4096);
  cvtTL<<<dim3((1024 / 32) * (4096 / 32), 8), 256, 0, stream>>>(fc2w, fc2T, 4096, 1024);

  for (int l = 0; l < 8; ++l) {
    // ---- attention ----
    ln_kernel<<<TSEQ, 256, 0, stream>>>(h, ln1w + l * 1024, ln1b + l * 1024, y);
    gemm_bt<0, 128><<<dim3(24, 16, 1), 256, 0, stream>>>(
        y, attnT + (size_t)l * 3072 * 1024, attb + l * 3072, qkb, vt, nullptr,
        2048, 3072, 1024);
    attn_fused<<<dim3(32, 16), 256, 0, stream>>>(qkb, vt, att);
    gemm_bt<1, 64><<<dim3(8, 32, 2), 256, 0, stream>>>(
        att, projT + (size_t)l * 1024 * 1024, projb + l * 1024, nullptr, nullptr,
        h, 2048, 1024, 1024);
    // ---- MLP ----
    ln_kernel<<<TSEQ, 256, 0, stream>>>(h, ln2w + l * 1024, ln2b + l * 1024, y);
    gemm_bt<2, 128><<<dim3(32, 16, 1), 256, 0, stream>>>(
        y, fcT + (size_t)l * 4096 * 1024, fcb + l * 4096, mid, nullptr, nullptr,
        2048, 4096, 1024);
    gemm_bt<1, 64><<<dim3(8, 32, 2), 256, 0, stream>>>(
        mid, fc2T + (size_t)l * 4096 * 1024, fc2b + l * 1024, nullptr, nullptr,
        h, 2048, 1024, 4096);
  }

  hipMemcpyAsync(d_out, h, (size_t)TSEQ * EDIM * 4, hipMemcpyDeviceToDevice, stream);
}